// Round 1
// baseline (542.694 us; speedup 1.0000x reference)
//
#include <hip/hip_runtime.h>
#include <hip/hip_fp16.h>

namespace {

constexpr int B = 2, C = 256, T = 2304, F = 1024, NH = 8, HD = 32;
constexpr int BH = B * NH;           // 16
constexpr int NCHUNK = 4;
constexpr int CHUNK = T / NCHUNK;    // 576
constexpr float SCALE = 0.17677669529663687f;  // 1/sqrt(32)

// workspace layout (bytes)
constexpr size_t SZ_H  = (size_t)B * C * T * 2;   // half [B,C,T]
constexpr size_t SZ_F  = (size_t)B * C * T * 4;   // float [B,C,T]
constexpr size_t OFF_Q  = 0;
constexpr size_t OFF_K  = OFF_Q + SZ_H;
constexpr size_t OFF_V  = OFF_K + SZ_H;
constexpr size_t OFF_AO = OFF_V + SZ_H;
constexpr size_t OFF_X1 = OFF_AO + SZ_H;
constexpr size_t OFF_UNION = OFF_X1 + SZ_F;   // attn partials first, then h16
constexpr size_t SZ_OPART  = (size_t)NCHUNK * BH * T * HD * 4;
constexpr size_t SZ_MPART  = (size_t)NCHUNK * BH * T * 4;
constexpr size_t OFF_OPART = OFF_UNION;
constexpr size_t OFF_MPART = OFF_OPART + SZ_OPART;
constexpr size_t OFF_LPART = OFF_MPART + SZ_MPART;
constexpr size_t OFF_H16   = OFF_UNION;       // reused after attention phase
constexpr size_t OFF_STATS = OFF_LPART + SZ_MPART;

} // namespace

// out[b][co][t] = act( W[co][:] . X[b][:][t] + bias[co] (+ res[b][co][t]) )
template<bool RELU, bool RES, typename InT, typename OutT>
__global__ __launch_bounds__(256)
void gemm_ct(const float* __restrict__ W, const InT* __restrict__ X,
             const float* __restrict__ bias, const float* __restrict__ res,
             OutT* __restrict__ out, int CO, int K)
{
  const int b   = blockIdx.z;
  const int co0 = blockIdx.y * 64;
  const int t0  = blockIdx.x * 64;
  const int tid = threadIdx.x;
  const int tx = tid & 15, ty = tid >> 4;
  __shared__ float As[16][68];   // [kk][co_i], padded for aligned b128 reads
  __shared__ float Bs[16][64];   // [kk][t_j]
  float acc[4][4] = {};
  const float* Wp = W + (size_t)co0 * K;
  const InT*   Xp = X + (size_t)b * K * T + t0;
  for (int k0 = 0; k0 < K; k0 += 16) {
#pragma unroll
    for (int l = 0; l < 4; ++l) {
      int idx = tid + l * 256;
      int coi = idx >> 4, kk = idx & 15;
      As[kk][coi] = Wp[(size_t)coi * K + k0 + kk];
    }
#pragma unroll
    for (int l = 0; l < 4; ++l) {
      int idx = tid + l * 256;
      int kk = idx >> 6, tj = idx & 63;
      Bs[kk][tj] = (float)Xp[(size_t)(k0 + kk) * T + tj];
    }
    __syncthreads();
#pragma unroll
    for (int kk = 0; kk < 16; ++kk) {
      float a[4], bl[4];
#pragma unroll
      for (int i = 0; i < 4; ++i) a[i] = As[kk][ty * 4 + i];
#pragma unroll
      for (int j = 0; j < 4; ++j) bl[j] = Bs[kk][tx * 4 + j];
#pragma unroll
      for (int i = 0; i < 4; ++i)
#pragma unroll
        for (int j = 0; j < 4; ++j)
          acc[i][j] = fmaf(a[i], bl[j], acc[i][j]);
    }
    __syncthreads();
  }
#pragma unroll
  for (int i = 0; i < 4; ++i) {
    const int co = co0 + ty * 4 + i;
    const float bi = bias[co];
#pragma unroll
    for (int j = 0; j < 4; ++j) {
      const int t = t0 + tx * 4 + j;
      float v = acc[i][j] + bi;
      if (RES) v += res[((size_t)b * CO + co) * T + t];
      if (RELU) v = fmaxf(v, 0.f);
      out[((size_t)b * CO + co) * T + t] = (OutT)v;
    }
  }
}

// Flash attention partials over a key chunk. 1 wave / 64 queries.
// Q/K/V layout: [BH][HD][T] fp16 (== [B,C,T] with c = h*32+d).
__global__ __launch_bounds__(64)
void attn_partial(const __half* __restrict__ Q, const __half* __restrict__ Kh,
                  const __half* __restrict__ Vh, float* __restrict__ opart,
                  float* __restrict__ mpart, float* __restrict__ lpart)
{
  const int tq = threadIdx.x;
  const int q  = blockIdx.x * 64 + tq;
  const int chunk = blockIdx.y;
  const int bh = blockIdx.z;
  const size_t base = (size_t)bh * HD * T;
  float qr[HD];
#pragma unroll
  for (int d = 0; d < HD; ++d)
    qr[d] = (float)Q[base + (size_t)d * T + q] * SCALE;
  __shared__ float kl[64][36];   // pad 36 -> 16B-aligned rows for b128 reads
  __shared__ float vl[64][36];
  float m = -1e30f, l = 0.f;
  float o[HD];
#pragma unroll
  for (int d = 0; d < HD; ++d) o[d] = 0.f;
  const int kc0 = chunk * CHUNK;
  for (int kt = 0; kt < CHUNK; kt += 64) {
    __syncthreads();
#pragma unroll
    for (int d = 0; d < HD; ++d) {
      kl[tq][d] = (float)Kh[base + (size_t)d * T + kc0 + kt + tq];
      vl[tq][d] = (float)Vh[base + (size_t)d * T + kc0 + kt + tq];
    }
    __syncthreads();
#pragma unroll 1
    for (int kk = 0; kk < 64; kk += 4) {
      float s0 = 0, s1 = 0, s2 = 0, s3 = 0;
#pragma unroll
      for (int d = 0; d < HD; ++d) {
        const float qd = qr[d];
        s0 = fmaf(qd, kl[kk + 0][d], s0);
        s1 = fmaf(qd, kl[kk + 1][d], s1);
        s2 = fmaf(qd, kl[kk + 2][d], s2);
        s3 = fmaf(qd, kl[kk + 3][d], s3);
      }
      const float mt = fmaxf(fmaxf(fmaxf(s0, s1), fmaxf(s2, s3)), m);
      const float f  = __expf(m - mt);
      const float e0 = __expf(s0 - mt), e1 = __expf(s1 - mt);
      const float e2 = __expf(s2 - mt), e3 = __expf(s3 - mt);
      l = l * f + (e0 + e1 + e2 + e3);
#pragma unroll
      for (int d = 0; d < HD; ++d) {
        float a = o[d] * f;
        a = fmaf(e0, vl[kk + 0][d], a);
        a = fmaf(e1, vl[kk + 1][d], a);
        a = fmaf(e2, vl[kk + 2][d], a);
        a = fmaf(e3, vl[kk + 3][d], a);
        o[d] = a;
      }
      m = mt;
    }
  }
  const size_t pb = (size_t)(chunk * BH + bh) * T + q;
  mpart[pb] = m;
  lpart[pb] = l;
  float4* op = (float4*)(opart + pb * HD);
#pragma unroll
  for (int d4 = 0; d4 < HD / 4; ++d4)
    op[d4] = make_float4(o[4 * d4], o[4 * d4 + 1], o[4 * d4 + 2], o[4 * d4 + 3]);
}

// Combine key-chunk partials + remove component along normalized v (fp16 cast points).
__global__ __launch_bounds__(64)
void attn_combine(const float* __restrict__ opart, const float* __restrict__ mpart,
                  const float* __restrict__ lpart, const __half* __restrict__ Vh,
                  __half* __restrict__ AO)
{
  const int q  = blockIdx.x * 64 + threadIdx.x;
  const int bh = blockIdx.y;
  float mv[NCHUNK], lv[NCHUNK];
  float M = -1e30f;
#pragma unroll
  for (int c = 0; c < NCHUNK; ++c) {
    const size_t pb = (size_t)(c * BH + bh) * T + q;
    mv[c] = mpart[pb];
    lv[c] = lpart[pb];
    M = fmaxf(M, mv[c]);
  }
  float L = 0.f;
  float wc[NCHUNK];
#pragma unroll
  for (int c = 0; c < NCHUNK; ++c) { wc[c] = __expf(mv[c] - M); L = fmaf(lv[c], wc[c], L); }
  const float inv = 1.f / L;
  float o[HD];
#pragma unroll
  for (int d = 0; d < HD; ++d) o[d] = 0.f;
#pragma unroll
  for (int c = 0; c < NCHUNK; ++c) {
    const size_t pb = (size_t)(c * BH + bh) * T + q;
    const float4* op = (const float4*)(opart + pb * HD);
#pragma unroll
    for (int d4 = 0; d4 < HD / 4; ++d4) {
      float4 t4 = op[d4];
      o[4 * d4 + 0] = fmaf(wc[c], t4.x, o[4 * d4 + 0]);
      o[4 * d4 + 1] = fmaf(wc[c], t4.y, o[4 * d4 + 1]);
      o[4 * d4 + 2] = fmaf(wc[c], t4.z, o[4 * d4 + 2]);
      o[4 * d4 + 3] = fmaf(wc[c], t4.w, o[4 * d4 + 3]);
    }
  }
  const size_t base = (size_t)bh * HD * T + q;
  float vv[HD], nrm2 = 0.f;
#pragma unroll
  for (int d = 0; d < HD; ++d) {
    vv[d] = (float)Vh[base + (size_t)d * T];
    nrm2 = fmaf(vv[d], vv[d], nrm2);
  }
  const float nrm = fmaxf(sqrtf(nrm2), 1e-12f);
  float dot = 0.f;
  float o16[HD], vn[HD];
#pragma unroll
  for (int d = 0; d < HD; ++d) {
    o16[d] = (float)(__half)(o[d] * inv);
    vn[d]  = (float)(__half)(vv[d] / nrm);
    dot = fmaf(o16[d], vn[d], dot);
  }
#pragma unroll
  for (int d = 0; d < HD; ++d)
    AO[base + (size_t)d * T] = (__half)(o16[d] - dot * vn[d]);
}

__global__ void zero_stats(float* stats)
{
  if (threadIdx.x < 8) stats[threadIdx.x] = 0.f;
}

__global__ __launch_bounds__(256)
void gn_stats(const float* __restrict__ X, float* __restrict__ stats)
{
  const int b = blockIdx.y;
  const float* xp = X + (size_t)b * C * T;
  const int n = C * T;
  float s = 0.f, s2 = 0.f;
  for (int i = blockIdx.x * 256 + threadIdx.x; i < n; i += 64 * 256) {
    float v = xp[i];
    s += v;
    s2 = fmaf(v, v, s2);
  }
#pragma unroll
  for (int off = 32; off > 0; off >>= 1) {
    s  += __shfl_down(s, off);
    s2 += __shfl_down(s2, off);
  }
  __shared__ float rs[4], rs2[4];
  const int wid = threadIdx.x >> 6, lane = threadIdx.x & 63;
  if (lane == 0) { rs[wid] = s; rs2[wid] = s2; }
  __syncthreads();
  if (threadIdx.x == 0) {
    atomicAdd(&stats[b * 2],     rs[0] + rs[1] + rs[2] + rs[3]);
    atomicAdd(&stats[b * 2 + 1], rs2[0] + rs2[1] + rs2[2] + rs2[3]);
  }
}

__global__ __launch_bounds__(256)
void gn_norm(const float* __restrict__ Y, const float* __restrict__ stats,
             const float* __restrict__ gamma, const float* __restrict__ beta,
             float* __restrict__ O)
{
  const int i = blockIdx.x * 256 + threadIdx.x;
  const int b = i / (C * T);
  const int c = (i / T) & (C - 1);
  const float invN = 1.f / (float)(C * T);
  const float mu  = stats[b * 2] * invN;
  const float var = stats[b * 2 + 1] * invN - mu * mu;
  const float r = rsqrtf(var + 1e-5f);
  O[i] = (Y[i] - mu) * r * gamma[c] + beta[c];
}

extern "C" void kernel_launch(void* const* d_in, const int* in_sizes, int n_in,
                              void* d_out, int out_size, void* d_ws, size_t ws_size,
                              hipStream_t stream)
{
  const float* x      = (const float*)d_in[0];
  const float* wq     = (const float*)d_in[1];
  const float* bq     = (const float*)d_in[2];
  const float* wk     = (const float*)d_in[3];
  const float* bk     = (const float*)d_in[4];
  const float* wv     = (const float*)d_in[5];
  const float* bv     = (const float*)d_in[6];
  const float* wo     = (const float*)d_in[7];
  const float* bo     = (const float*)d_in[8];
  const float* gamma1 = (const float*)d_in[9];
  const float* beta1  = (const float*)d_in[10];
  const float* w1     = (const float*)d_in[11];
  const float* bf1    = (const float*)d_in[12];
  const float* w2     = (const float*)d_in[13];
  const float* bf2    = (const float*)d_in[14];
  const float* gamma2 = (const float*)d_in[15];
  const float* beta2  = (const float*)d_in[16];

  char* ws = (char*)d_ws;
  __half* q16   = (__half*)(ws + OFF_Q);
  __half* k16   = (__half*)(ws + OFF_K);
  __half* v16   = (__half*)(ws + OFF_V);
  __half* ao16  = (__half*)(ws + OFF_AO);
  float*  x1    = (float*)(ws + OFF_X1);
  float*  opart = (float*)(ws + OFF_OPART);
  float*  mpart = (float*)(ws + OFF_MPART);
  float*  lpart = (float*)(ws + OFF_LPART);
  __half* h16   = (__half*)(ws + OFF_H16);
  float*  stats = (float*)(ws + OFF_STATS);
  float*  out   = (float*)d_out;

  const dim3 blk256(256);

  zero_stats<<<1, 64, 0, stream>>>(stats);

  // QKV projections (fp32 accumulate, store fp16) -- [B,C,T] layout
  gemm_ct<false, false, float, __half><<<dim3(36, 4, 2), blk256, 0, stream>>>(wq, x, bq, nullptr, q16, C, C);
  gemm_ct<false, false, float, __half><<<dim3(36, 4, 2), blk256, 0, stream>>>(wk, x, bk, nullptr, k16, C, C);
  gemm_ct<false, false, float, __half><<<dim3(36, 4, 2), blk256, 0, stream>>>(wv, x, bv, nullptr, v16, C, C);

  // Flash attention with 4-way key split + combine (incl. vn correction)
  attn_partial<<<dim3(36, NCHUNK, BH), dim3(64), 0, stream>>>(q16, k16, v16, opart, mpart, lpart);
  attn_combine<<<dim3(36, BH), dim3(64), 0, stream>>>(opart, mpart, lpart, v16, ao16);

  // Output projection + residual -> y1 (in x1 buffer)
  gemm_ct<false, true, __half, float><<<dim3(36, 4, 2), blk256, 0, stream>>>(wo, ao16, bo, x, x1, C, C);

  // GroupNorm 1 (in place -> x1)
  gn_stats<<<dim3(64, 2), blk256, 0, stream>>>(x1, stats);
  gn_norm<<<dim3(4608), blk256, 0, stream>>>(x1, stats, gamma1, beta1, x1);

  // FFN
  gemm_ct<true,  false, float,  __half><<<dim3(36, 16, 2), blk256, 0, stream>>>(w1, x1, bf1, nullptr, h16, F, C);
  gemm_ct<false, true,  __half, float ><<<dim3(36, 4, 2),  blk256, 0, stream>>>(w2, h16, bf2, x1, out, C, F);

  // GroupNorm 2 (in place on d_out)
  gn_stats<<<dim3(64, 2), blk256, 0, stream>>>(out, stats + 4);
  gn_norm<<<dim3(4608), blk256, 0, stream>>>(out, stats + 4, gamma2, beta2, out);
}

// Round 2
// 283.323 us; speedup vs baseline: 1.9155x; 1.9155x over previous
//
#include <hip/hip_runtime.h>
#include <hip/hip_fp16.h>

typedef _Float16 f16x8 __attribute__((ext_vector_type(8)));
typedef float f32x4 __attribute__((ext_vector_type(4)));

namespace {

constexpr int B = 2, C = 256, T = 2304, F = 1024, NH = 8, HD = 32;
constexpr int BH = B * NH;           // 16
constexpr float SCALE = 0.17677669529663687f;  // 1/sqrt(32)

// workspace layout (bytes)
constexpr size_t SZ_H  = (size_t)B * C * T * 2;   // half [B,C,T]
constexpr size_t SZ_F  = (size_t)B * C * T * 4;   // float [B,C,T]
constexpr size_t OFF_Q  = 0;
constexpr size_t OFF_K  = OFF_Q + SZ_H;
constexpr size_t OFF_V  = OFF_K + SZ_H;
constexpr size_t OFF_AO = OFF_V + SZ_H;
constexpr size_t OFF_X1 = OFF_AO + SZ_H;
constexpr size_t OFF_H16   = OFF_X1 + SZ_F;       // half [B,F,T]
constexpr size_t OFF_STATS = OFF_H16 + (size_t)B * F * T * 2;

} // namespace

// out[b][co][t] = act( W[co][:] . X[b][:][t] + bias[co] (+ res[b][co][t]) )
template<bool RELU, bool RES, typename InT, typename OutT>
__global__ __launch_bounds__(256)
void gemm_ct(const float* __restrict__ W, const InT* __restrict__ X,
             const float* __restrict__ bias, const float* __restrict__ res,
             OutT* __restrict__ out, int CO, int K)
{
  const int b   = blockIdx.z;
  const int co0 = blockIdx.y * 64;
  const int t0  = blockIdx.x * 64;
  const int tid = threadIdx.x;
  const int tx = tid & 15, ty = tid >> 4;
  __shared__ float As[16][68];
  __shared__ float Bs[16][64];
  float acc[4][4] = {};
  const float* Wp = W + (size_t)co0 * K;
  const InT*   Xp = X + (size_t)b * K * T + t0;
  for (int k0 = 0; k0 < K; k0 += 16) {
#pragma unroll
    for (int l = 0; l < 4; ++l) {
      int idx = tid + l * 256;
      int coi = idx >> 4, kk = idx & 15;
      As[kk][coi] = Wp[(size_t)coi * K + k0 + kk];
    }
#pragma unroll
    for (int l = 0; l < 4; ++l) {
      int idx = tid + l * 256;
      int kk = idx >> 6, tj = idx & 63;
      Bs[kk][tj] = (float)Xp[(size_t)(k0 + kk) * T + tj];
    }
    __syncthreads();
#pragma unroll
    for (int kk = 0; kk < 16; ++kk) {
      float a[4], bl[4];
#pragma unroll
      for (int i = 0; i < 4; ++i) a[i] = As[kk][ty * 4 + i];
#pragma unroll
      for (int j = 0; j < 4; ++j) bl[j] = Bs[kk][tx * 4 + j];
#pragma unroll
      for (int i = 0; i < 4; ++i)
#pragma unroll
        for (int j = 0; j < 4; ++j)
          acc[i][j] = fmaf(a[i], bl[j], acc[i][j]);
    }
    __syncthreads();
  }
#pragma unroll
  for (int i = 0; i < 4; ++i) {
    const int co = co0 + ty * 4 + i;
    const float bi = bias[co];
#pragma unroll
    for (int j = 0; j < 4; ++j) {
      const int t = t0 + tx * 4 + j;
      float v = acc[i][j] + bi;
      if (RES) v += res[((size_t)b * CO + co) * T + t];
      if (RELU) v = fmaxf(v, 0.f);
      out[((size_t)b * CO + co) * T + t] = (OutT)v;
    }
  }
}

// Fused MFMA flash attention + vhat-removal.
// Q/K/V layout: [BH][HD][T] f16. Block: 4 waves, each owns 16 queries.
__global__ __launch_bounds__(256)
void attn_mfma(const __half* __restrict__ Qh, const __half* __restrict__ Kh,
               const __half* __restrict__ Vh, __half* __restrict__ AOh)
{
  const int tid  = threadIdx.x;
  const int wid  = tid >> 6;
  const int lane = tid & 63;
  const int g    = lane >> 4;      // 0..3
  const int lo   = lane & 15;
  const int bh   = blockIdx.y;
  const int tq   = blockIdx.x * 64 + wid * 16 + lo;  // this lane's query column
  const size_t base = (size_t)bh * HD * T;
  const _Float16* Q = (const _Float16*)Qh;
  const _Float16* K = (const _Float16*)Kh;
  const _Float16* V = (const _Float16*)Vh;

  __shared__ _Float16 kt[64][36];   // [tk][d] transposed K tile (pad 36)
  __shared__ _Float16 vt[32][72];   // [d][tk] natural V tile (pad 72)

  // Q fragment (B operand): qf[j] = Q[8g+j][tq]
  f16x8 qf;
#pragma unroll
  for (int j = 0; j < 8; ++j)
    qf[j] = Q[base + (size_t)(8 * g + j) * T + tq];

  const f32x4 zero4 = {0.f, 0.f, 0.f, 0.f};
  f32x4 oa[2] = {zero4, zero4};    // O[d = dt*16 + 4g + r][tq]
  float m = -1e30f, l = 0.f;

  for (int it = 0; it < T / 64; ++it) {
    const int tk0 = it * 64;
    __syncthreads();
    // ---- stage K transposed: kt[t][d] = K[d][tk0+t] (half2 writes)
    {
      const int t = tid & 63;
      const int dp0 = tid >> 6;  // 0..3
#pragma unroll
      for (int dd = 0; dd < 4; ++dd) {
        const int d = (dp0 * 4 + dd) * 2;
        const ushort klo = *(const ushort*)(K + base + (size_t)d * T + tk0 + t);
        const ushort khi = *(const ushort*)(K + base + (size_t)(d + 1) * T + tk0 + t);
        *(uint*)&kt[t][d] = (uint)klo | ((uint)khi << 16);
      }
    }
    // ---- stage V natural: vt[d][t] = V[d][tk0+t] (16B copies)
    {
      const int dv = tid >> 3;   // 0..31
      const int seg = tid & 7;   // 0..7
      *(uint4*)&vt[dv][seg * 8] =
          *(const uint4*)(V + base + (size_t)dv * T + tk0 + seg * 8);
    }
    __syncthreads();

    // ---- QK^T (swapped): S^T tile = mfma(K_frag, Q_frag)
    f32x4 s4[4];
#pragma unroll
    for (int mt = 0; mt < 4; ++mt) {
      union { f16x8 v; uint2 u[2]; } kf;
      const _Float16* kr = &kt[mt * 16 + lo][8 * g];
      kf.u[0] = *(const uint2*)(kr);
      kf.u[1] = *(const uint2*)(kr + 4);
      s4[mt] = __builtin_amdgcn_mfma_f32_16x16x32_f16(kf.v, qf, zero4, 0, 0, 0);
    }
    // lane holds S[tq][tk = mt*16 + 4g + r]
    float p[4][4];
    float rmax = -1e30f;
#pragma unroll
    for (int mt = 0; mt < 4; ++mt)
#pragma unroll
      for (int r = 0; r < 4; ++r) {
        p[mt][r] = s4[mt][r] * SCALE;
        rmax = fmaxf(rmax, p[mt][r]);
      }
    rmax = fmaxf(rmax, __shfl_xor(rmax, 16));
    rmax = fmaxf(rmax, __shfl_xor(rmax, 32));
    const float mn = fmaxf(m, rmax);
    const float fsc = __expf(m - mn);
    m = mn;
    float psum = 0.f;
#pragma unroll
    for (int mt = 0; mt < 4; ++mt)
#pragma unroll
      for (int r = 0; r < 4; ++r) {
        p[mt][r] = __expf(p[mt][r] - mn);
        psum += p[mt][r];
      }
    psum += __shfl_xor(psum, 16);
    psum += __shfl_xor(psum, 32);
    l = l * fsc + psum;
#pragma unroll
    for (int dt = 0; dt < 2; ++dt)
#pragma unroll
      for (int r = 0; r < 4; ++r) oa[dt][r] *= fsc;

    // ---- PV: per 32-key chunk, build P B-fragment via shuffles, 2 d-tiles
#pragma unroll
    for (int c2 = 0; c2 < 2; ++c2) {
      union { f16x8 v; _Float16 e[8]; } pb;
#pragma unroll
      for (int j = 0; j < 8; ++j) {
        const int srcl = lo | ((2 * (g & 1) + (j >> 2)) << 4);
        const float v0 = __shfl(p[2 * c2][j & 3], srcl, 64);
        const float v1 = __shfl(p[2 * c2 + 1][j & 3], srcl, 64);
        pb.e[j] = (_Float16)(g < 2 ? v0 : v1);
      }
#pragma unroll
      for (int dt = 0; dt < 2; ++dt) {
        const f16x8 vf = *(const f16x8*)&vt[dt * 16 + lo][c2 * 32 + 8 * g];
        oa[dt] = __builtin_amdgcn_mfma_f32_16x16x32_f16(vf, pb.v, oa[dt], 0, 0, 0);
      }
    }
  }

  // ---- epilogue: normalize, remove component along normalized v, store
  const float invL = 1.f / l;
  float vv[8], n2 = 0.f;
#pragma unroll
  for (int dt = 0; dt < 2; ++dt)
#pragma unroll
    for (int r = 0; r < 4; ++r) {
      const float x = (float)V[base + (size_t)(dt * 16 + 4 * g + r) * T + tq];
      vv[dt * 4 + r] = x;
      n2 = fmaf(x, x, n2);
    }
  n2 += __shfl_xor(n2, 16);
  n2 += __shfl_xor(n2, 32);
  const float nrm = fmaxf(sqrtf(n2), 1e-12f);
  float o16[8], vn[8], dp = 0.f;
#pragma unroll
  for (int dt = 0; dt < 2; ++dt)
#pragma unroll
    for (int r = 0; r < 4; ++r) {
      const int i = dt * 4 + r;
      o16[i] = (float)(_Float16)(oa[dt][r] * invL);
      vn[i]  = (float)(_Float16)(vv[i] / nrm);
      dp = fmaf(o16[i], vn[i], dp);
    }
  dp += __shfl_xor(dp, 16);
  dp += __shfl_xor(dp, 32);
#pragma unroll
  for (int dt = 0; dt < 2; ++dt)
#pragma unroll
    for (int r = 0; r < 4; ++r) {
      const int i = dt * 4 + r;
      AOh[base + (size_t)(dt * 16 + 4 * g + r) * T + tq] =
          (__half)(o16[i] - dp * vn[i]);
    }
}

__global__ void zero_stats(float* stats)
{
  if (threadIdx.x < 8) stats[threadIdx.x] = 0.f;
}

__global__ __launch_bounds__(256)
void gn_stats(const float* __restrict__ X, float* __restrict__ stats)
{
  const int b = blockIdx.y;
  const float* xp = X + (size_t)b * C * T;
  const int n = C * T;
  float s = 0.f, s2 = 0.f;
  for (int i = blockIdx.x * 256 + threadIdx.x; i < n; i += 64 * 256) {
    float v = xp[i];
    s += v;
    s2 = fmaf(v, v, s2);
  }
#pragma unroll
  for (int off = 32; off > 0; off >>= 1) {
    s  += __shfl_down(s, off);
    s2 += __shfl_down(s2, off);
  }
  __shared__ float rs[4], rs2[4];
  const int wid = threadIdx.x >> 6, lane = threadIdx.x & 63;
  if (lane == 0) { rs[wid] = s; rs2[wid] = s2; }
  __syncthreads();
  if (threadIdx.x == 0) {
    atomicAdd(&stats[b * 2],     rs[0] + rs[1] + rs[2] + rs[3]);
    atomicAdd(&stats[b * 2 + 1], rs2[0] + rs2[1] + rs2[2] + rs2[3]);
  }
}

__global__ __launch_bounds__(256)
void gn_norm(const float* __restrict__ Y, const float* __restrict__ stats,
             const float* __restrict__ gamma, const float* __restrict__ beta,
             float* __restrict__ O)
{
  const int i = blockIdx.x * 256 + threadIdx.x;
  const int b = i / (C * T);
  const int c = (i / T) & (C - 1);
  const float invN = 1.f / (float)(C * T);
  const float mu  = stats[b * 2] * invN;
  const float var = stats[b * 2 + 1] * invN - mu * mu;
  const float r = rsqrtf(var + 1e-5f);
  O[i] = (Y[i] - mu) * r * gamma[c] + beta[c];
}

extern "C" void kernel_launch(void* const* d_in, const int* in_sizes, int n_in,
                              void* d_out, int out_size, void* d_ws, size_t ws_size,
                              hipStream_t stream)
{
  const float* x      = (const float*)d_in[0];
  const float* wq     = (const float*)d_in[1];
  const float* bq     = (const float*)d_in[2];
  const float* wk     = (const float*)d_in[3];
  const float* bk     = (const float*)d_in[4];
  const float* wv     = (const float*)d_in[5];
  const float* bv     = (const float*)d_in[6];
  const float* wo     = (const float*)d_in[7];
  const float* bo     = (const float*)d_in[8];
  const float* gamma1 = (const float*)d_in[9];
  const float* beta1  = (const float*)d_in[10];
  const float* w1     = (const float*)d_in[11];
  const float* bf1    = (const float*)d_in[12];
  const float* w2     = (const float*)d_in[13];
  const float* bf2    = (const float*)d_in[14];
  const float* gamma2 = (const float*)d_in[15];
  const float* beta2  = (const float*)d_in[16];

  char* ws = (char*)d_ws;
  __half* q16   = (__half*)(ws + OFF_Q);
  __half* k16   = (__half*)(ws + OFF_K);
  __half* v16   = (__half*)(ws + OFF_V);
  __half* ao16  = (__half*)(ws + OFF_AO);
  float*  x1    = (float*)(ws + OFF_X1);
  __half* h16   = (__half*)(ws + OFF_H16);
  float*  stats = (float*)(ws + OFF_STATS);
  float*  out   = (float*)d_out;

  const dim3 blk256(256);

  zero_stats<<<1, 64, 0, stream>>>(stats);

  // QKV projections (fp32 accumulate, store fp16) -- [B,C,T] layout
  gemm_ct<false, false, float, __half><<<dim3(36, 4, 2), blk256, 0, stream>>>(wq, x, bq, nullptr, q16, C, C);
  gemm_ct<false, false, float, __half><<<dim3(36, 4, 2), blk256, 0, stream>>>(wk, x, bk, nullptr, k16, C, C);
  gemm_ct<false, false, float, __half><<<dim3(36, 4, 2), blk256, 0, stream>>>(wv, x, bv, nullptr, v16, C, C);

  // Fused MFMA flash attention (incl. vn correction)
  attn_mfma<<<dim3(T / 64, BH), blk256, 0, stream>>>(q16, k16, v16, ao16);

  // Output projection + residual -> x1
  gemm_ct<false, true, __half, float><<<dim3(36, 4, 2), blk256, 0, stream>>>(wo, ao16, bo, x, x1, C, C);

  // GroupNorm 1 (in place -> x1)
  gn_stats<<<dim3(64, 2), blk256, 0, stream>>>(x1, stats);
  gn_norm<<<dim3(4608), blk256, 0, stream>>>(x1, stats, gamma1, beta1, x1);

  // FFN
  gemm_ct<true,  false, float,  __half><<<dim3(36, 16, 2), blk256, 0, stream>>>(w1, x1, bf1, nullptr, h16, F, C);
  gemm_ct<false, true,  __half, float ><<<dim3(36, 4, 2),  blk256, 0, stream>>>(w2, h16, bf2, x1, out, C, F);

  // GroupNorm 2 (in place on d_out)
  gn_stats<<<dim3(64, 2), blk256, 0, stream>>>(out, stats + 4);
  gn_norm<<<dim3(4608), blk256, 0, stream>>>(out, stats + 4, gamma2, beta2, out);
}

// Round 3
// 169.208 us; speedup vs baseline: 3.2073x; 1.6744x over previous
//
#include <hip/hip_runtime.h>
#include <hip/hip_fp16.h>

typedef _Float16 f16x8 __attribute__((ext_vector_type(8)));
typedef float f32x4 __attribute__((ext_vector_type(4)));

namespace {

constexpr int B = 2, C = 256, T = 2304, F = 1024, NH = 8, HD = 32;
constexpr int BH = B * NH;           // 16
constexpr float SCALE = 0.17677669529663687f;  // 1/sqrt(32)
constexpr float INV_N = 1.0f / (float)(C * T);

// f16 weight block sizes (flat elements)
constexpr size_t N_WQKV = (size_t)3 * C * C;   // 196608
constexpr size_t N_WO   = (size_t)C * C;       // 65536
constexpr size_t N_W1   = (size_t)F * C;       // 262144
constexpr size_t N_W2   = (size_t)C * F;       // 262144
constexpr size_t N_WALL = N_WQKV + N_WO + N_W1 + N_W2;

// workspace layout (bytes)
constexpr size_t OFF_QKV  = 0;                                // f16 [B][3C][T]
constexpr size_t SZ_QKV   = (size_t)B * 3 * C * T * 2;
constexpr size_t OFF_AO   = OFF_QKV + SZ_QKV;                 // f16 [B][C][T]
constexpr size_t SZ_AO    = (size_t)B * C * T * 2;
constexpr size_t OFF_X1   = OFF_AO + SZ_AO;                   // f32 [B][C][T] (raw, pre-GN1)
constexpr size_t SZ_X1    = (size_t)B * C * T * 4;
constexpr size_t OFF_H16  = OFF_X1 + SZ_X1;                   // f16 [B][F][T]
constexpr size_t SZ_H16   = (size_t)B * F * T * 2;
constexpr size_t OFF_W16  = OFF_H16 + SZ_H16;                 // f16 weights (qkv|wo|w1|w2)
constexpr size_t OFF_BQKV = OFF_W16 + N_WALL * 2;             // f32 [768]
constexpr size_t OFF_STATS = OFF_BQKV + (size_t)3 * C * 4;    // f32 [8]

} // namespace

// Convert all weights fp32 -> f16 into one flat buffer; concat qkv bias; zero stats.
__global__ __launch_bounds__(256)
void convert_weights(const float* __restrict__ wq, const float* __restrict__ wk,
                     const float* __restrict__ wv, const float* __restrict__ wo,
                     const float* __restrict__ w1, const float* __restrict__ w2,
                     const float* __restrict__ bq, const float* __restrict__ bk,
                     const float* __restrict__ bv,
                     _Float16* __restrict__ w16, float* __restrict__ bqkv,
                     float* __restrict__ stats)
{
  const size_t tid = (size_t)blockIdx.x * 256 + threadIdx.x;
  if (tid < 8) stats[tid] = 0.f;
  if (tid < 3 * C)
    bqkv[tid] = tid < C ? bq[tid] : (tid < 2 * C ? bk[tid - C] : bv[tid - 2 * C]);
  for (size_t i = tid; i < N_WALL; i += (size_t)gridDim.x * 256) {
    float v;
    if      (i < 65536)  v = wq[i];
    else if (i < 131072) v = wk[i - 65536];
    else if (i < 196608) v = wv[i - 131072];
    else if (i < 262144) v = wo[i - 196608];
    else if (i < 524288) v = w1[i - 262144];
    else                 v = w2[i - 524288];
    w16[i] = (_Float16)v;
  }
}

// out[b][co][t] = act( W[co][:] . X[b][:][t] + bias[co] (+ res') )
// 64x64 tile, 4 waves, each wave a 32x32 sub-tile via 2x2 mfma 16x16x32.
// GNIN: apply GroupNorm (stats_in, gamma, beta) to staged X.
// GNRES: apply GroupNorm to the residual term. STATS: accumulate sum/sumsq of
// outputs into stats_out[b*2 +{0,1}] via atomics.
template<bool RELU, bool RES, bool GNIN, bool GNRES, bool STATS,
         typename InT, typename OutT>
__global__ __launch_bounds__(256)
void gemm_mfma(const _Float16* __restrict__ W, const InT* __restrict__ X,
               const float* __restrict__ bias, const float* __restrict__ res,
               OutT* __restrict__ out, int CO, int K,
               const float* __restrict__ stats_in,
               const float* __restrict__ gamma, const float* __restrict__ beta,
               float* __restrict__ stats_out)
{
  const int b   = blockIdx.z;
  const int co0 = blockIdx.y * 64;
  const int t0  = blockIdx.x * 64;
  const int tid = threadIdx.x;
  const int wid = tid >> 6, lane = tid & 63;
  const int g = lane >> 4, lo = lane & 15;
  const int wm = wid & 1, wn = wid >> 1;

  __shared__ f16x8 xs[4][64];      // [k/8][t] current 32-k step
  __shared__ float gs[256], bs[256];
  __shared__ float red[8];

  float mu = 0.f, rsig = 0.f;
  if (GNIN || GNRES) {
    const float s1 = stats_in[b * 2], s2 = stats_in[b * 2 + 1];
    mu = s1 * INV_N;
    rsig = rsqrtf(s2 * INV_N - mu * mu + 1e-5f);
  }
  if (GNIN) { gs[tid] = gamma[tid]; bs[tid] = beta[tid]; }

  const f32x4 z4 = {0.f, 0.f, 0.f, 0.f};
  f32x4 acc00 = z4, acc01 = z4, acc10 = z4, acc11 = z4;

  const int st = tid & 63;   // staged t within tile
  const int kp = tid >> 6;   // staged k/8 within step
  const InT* Xp = X + (size_t)b * K * T + t0 + st;
  const _Float16* Wp = W + (size_t)(co0 + wm * 32 + lo) * K + 8 * g;

  __syncthreads();   // gs/bs visible before staging uses them

  for (int k0 = 0; k0 < K; k0 += 32) {
    f16x8 wv_;
#pragma unroll
    for (int j = 0; j < 8; ++j) {
      const int k = k0 + kp * 8 + j;
      float v = (float)Xp[(size_t)k * T];
      if (GNIN) v = (v - mu) * rsig * gs[k] + bs[k];
      wv_[j] = (_Float16)v;
    }
    xs[kp][st] = wv_;
    __syncthreads();
    const f16x8 af0 = *(const f16x8*)(Wp + (size_t)k0);
    const f16x8 af1 = *(const f16x8*)(Wp + (size_t)16 * K + k0);
    const f16x8 bf0 = xs[g][wn * 32 + lo];
    const f16x8 bf1 = xs[g][wn * 32 + 16 + lo];
    acc00 = __builtin_amdgcn_mfma_f32_16x16x32_f16(af0, bf0, acc00, 0, 0, 0);
    acc01 = __builtin_amdgcn_mfma_f32_16x16x32_f16(af0, bf1, acc01, 0, 0, 0);
    acc10 = __builtin_amdgcn_mfma_f32_16x16x32_f16(af1, bf0, acc10, 0, 0, 0);
    acc11 = __builtin_amdgcn_mfma_f32_16x16x32_f16(af1, bf1, acc11, 0, 0, 0);
    __syncthreads();
  }

  // epilogue: D row = mi*16 + 4g + r (co within 32), col = ni*16 + lo (t within 32)
  float s = 0.f, ss = 0.f;
  const size_t obase = ((size_t)b * CO + co0 + wm * 32) * T + t0 + wn * 32 + lo;
  const float* resb = res + obase;   // valid only if RES
  OutT* outb = out + obase;
  const f32x4 accs[2][2] = {{acc00, acc01}, {acc10, acc11}};
#pragma unroll
  for (int mi = 0; mi < 2; ++mi) {
#pragma unroll
    for (int r = 0; r < 4; ++r) {
      const int row = mi * 16 + 4 * g + r;
      const int co = co0 + wm * 32 + row;
      const float bi = bias[co];
      float gm = 0.f, bt = 0.f;
      if (GNRES) { gm = gamma[co]; bt = beta[co]; }
#pragma unroll
      for (int ni = 0; ni < 2; ++ni) {
        float v = accs[mi][ni][r] + bi;
        if (RES) {
          float rv = resb[(size_t)row * T + ni * 16];
          if (GNRES) rv = (rv - mu) * rsig * gm + bt;
          v += rv;
        }
        if (RELU) v = fmaxf(v, 0.f);
        outb[(size_t)row * T + ni * 16] = (OutT)v;
        if (STATS) { s += v; ss = fmaf(v, v, ss); }
      }
    }
  }

  if (STATS) {
#pragma unroll
    for (int off = 32; off > 0; off >>= 1) {
      s  += __shfl_down(s, off);
      ss += __shfl_down(ss, off);
    }
    if (lane == 0) { red[wid] = s; red[4 + wid] = ss; }
    __syncthreads();
    if (tid == 0) {
      atomicAdd(&stats_out[b * 2],     red[0] + red[1] + red[2] + red[3]);
      atomicAdd(&stats_out[b * 2 + 1], red[4] + red[5] + red[6] + red[7]);
    }
  }
}

// Fused MFMA flash attention + vhat-removal. QKV fused layout [B][3C][T] f16.
__global__ __launch_bounds__(256)
void attn_mfma(const _Float16* __restrict__ qkv, _Float16* __restrict__ AOh)
{
  const int tid  = threadIdx.x;
  const int wid  = tid >> 6;
  const int lane = tid & 63;
  const int g    = lane >> 4;
  const int lo   = lane & 15;
  const int bh   = blockIdx.y;
  const int b    = bh >> 3, h = bh & 7;
  const int tq   = blockIdx.x * 64 + wid * 16 + lo;
  const size_t qb = ((size_t)b * 3 * C + h * HD) * T;
  const size_t kb = qb + (size_t)C * T;
  const size_t vb = qb + (size_t)2 * C * T;
  const size_t ab = ((size_t)b * C + h * HD) * T;

  __shared__ _Float16 kt[64][36];
  __shared__ _Float16 vt[32][72];

  f16x8 qf;
#pragma unroll
  for (int j = 0; j < 8; ++j)
    qf[j] = qkv[qb + (size_t)(8 * g + j) * T + tq];

  const f32x4 zero4 = {0.f, 0.f, 0.f, 0.f};
  f32x4 oa[2] = {zero4, zero4};
  float m = -1e30f, l = 0.f;

  for (int it = 0; it < T / 64; ++it) {
    const int tk0 = it * 64;
    __syncthreads();
    {
      const int t = tid & 63;
      const int dp0 = tid >> 6;
#pragma unroll
      for (int dd = 0; dd < 4; ++dd) {
        const int d = (dp0 * 4 + dd) * 2;
        const ushort klo = *(const ushort*)(qkv + kb + (size_t)d * T + tk0 + t);
        const ushort khi = *(const ushort*)(qkv + kb + (size_t)(d + 1) * T + tk0 + t);
        *(uint*)&kt[t][d] = (uint)klo | ((uint)khi << 16);
      }
    }
    {
      const int dv = tid >> 3;
      const int seg = tid & 7;
      *(uint4*)&vt[dv][seg * 8] =
          *(const uint4*)(qkv + vb + (size_t)dv * T + tk0 + seg * 8);
    }
    __syncthreads();

    f32x4 s4[4];
#pragma unroll
    for (int mt = 0; mt < 4; ++mt) {
      union { f16x8 v; uint2 u[2]; } kf;
      const _Float16* kr = &kt[mt * 16 + lo][8 * g];
      kf.u[0] = *(const uint2*)(kr);
      kf.u[1] = *(const uint2*)(kr + 4);
      s4[mt] = __builtin_amdgcn_mfma_f32_16x16x32_f16(kf.v, qf, zero4, 0, 0, 0);
    }
    float p[4][4];
    float rmax = -1e30f;
#pragma unroll
    for (int mt = 0; mt < 4; ++mt)
#pragma unroll
      for (int r = 0; r < 4; ++r) {
        p[mt][r] = s4[mt][r] * SCALE;
        rmax = fmaxf(rmax, p[mt][r]);
      }
    rmax = fmaxf(rmax, __shfl_xor(rmax, 16));
    rmax = fmaxf(rmax, __shfl_xor(rmax, 32));
    const float mn = fmaxf(m, rmax);
    const float fsc = __expf(m - mn);
    m = mn;
    float psum = 0.f;
#pragma unroll
    for (int mt = 0; mt < 4; ++mt)
#pragma unroll
      for (int r = 0; r < 4; ++r) {
        p[mt][r] = __expf(p[mt][r] - mn);
        psum += p[mt][r];
      }
    psum += __shfl_xor(psum, 16);
    psum += __shfl_xor(psum, 32);
    l = l * fsc + psum;
#pragma unroll
    for (int dt = 0; dt < 2; ++dt)
#pragma unroll
      for (int r = 0; r < 4; ++r) oa[dt][r] *= fsc;

#pragma unroll
    for (int c2 = 0; c2 < 2; ++c2) {
      union { f16x8 v; _Float16 e[8]; } pb;
#pragma unroll
      for (int j = 0; j < 8; ++j) {
        const int srcl = lo | ((2 * (g & 1) + (j >> 2)) << 4);
        const float v0 = __shfl(p[2 * c2][j & 3], srcl, 64);
        const float v1 = __shfl(p[2 * c2 + 1][j & 3], srcl, 64);
        pb.e[j] = (_Float16)(g < 2 ? v0 : v1);
      }
#pragma unroll
      for (int dt = 0; dt < 2; ++dt) {
        const f16x8 vf = *(const f16x8*)&vt[dt * 16 + lo][c2 * 32 + 8 * g];
        oa[dt] = __builtin_amdgcn_mfma_f32_16x16x32_f16(vf, pb.v, oa[dt], 0, 0, 0);
      }
    }
  }

  const float invL = 1.f / l;
  float vv[8], n2 = 0.f;
#pragma unroll
  for (int dt = 0; dt < 2; ++dt)
#pragma unroll
    for (int r = 0; r < 4; ++r) {
      const float x = (float)qkv[vb + (size_t)(dt * 16 + 4 * g + r) * T + tq];
      vv[dt * 4 + r] = x;
      n2 = fmaf(x, x, n2);
    }
  n2 += __shfl_xor(n2, 16);
  n2 += __shfl_xor(n2, 32);
  const float nrm = fmaxf(sqrtf(n2), 1e-12f);
  float o16[8], vn[8], dp = 0.f;
#pragma unroll
  for (int dt = 0; dt < 2; ++dt)
#pragma unroll
    for (int r = 0; r < 4; ++r) {
      const int i = dt * 4 + r;
      o16[i] = (float)(_Float16)(oa[dt][r] * invL);
      vn[i]  = (float)(_Float16)(vv[i] / nrm);
      dp = fmaf(o16[i], vn[i], dp);
    }
  dp += __shfl_xor(dp, 16);
  dp += __shfl_xor(dp, 32);
#pragma unroll
  for (int dt = 0; dt < 2; ++dt)
#pragma unroll
    for (int r = 0; r < 4; ++r) {
      const int i = dt * 4 + r;
      AOh[ab + (size_t)(dt * 16 + 4 * g + r) * T + tq] =
          (_Float16)(o16[i] - dp * vn[i]);
    }
}

__global__ __launch_bounds__(256)
void gn_norm(const float* __restrict__ Y, const float* __restrict__ stats,
             const float* __restrict__ gamma, const float* __restrict__ beta,
             float* __restrict__ O)
{
  const int i = blockIdx.x * 256 + threadIdx.x;
  const int b = i / (C * T);
  const int c = (i / T) & (C - 1);
  const float mu  = stats[b * 2] * INV_N;
  const float var = stats[b * 2 + 1] * INV_N - mu * mu;
  const float r = rsqrtf(var + 1e-5f);
  O[i] = (Y[i] - mu) * r * gamma[c] + beta[c];
}

extern "C" void kernel_launch(void* const* d_in, const int* in_sizes, int n_in,
                              void* d_out, int out_size, void* d_ws, size_t ws_size,
                              hipStream_t stream)
{
  const float* x      = (const float*)d_in[0];
  const float* wq     = (const float*)d_in[1];
  const float* bq     = (const float*)d_in[2];
  const float* wk     = (const float*)d_in[3];
  const float* bk     = (const float*)d_in[4];
  const float* wv     = (const float*)d_in[5];
  const float* bv     = (const float*)d_in[6];
  const float* wo     = (const float*)d_in[7];
  const float* bo     = (const float*)d_in[8];
  const float* gamma1 = (const float*)d_in[9];
  const float* beta1  = (const float*)d_in[10];
  const float* w1     = (const float*)d_in[11];
  const float* bf1    = (const float*)d_in[12];
  const float* w2     = (const float*)d_in[13];
  const float* bf2    = (const float*)d_in[14];
  const float* gamma2 = (const float*)d_in[15];
  const float* beta2  = (const float*)d_in[16];

  char* ws = (char*)d_ws;
  _Float16* qkv16 = (_Float16*)(ws + OFF_QKV);
  _Float16* ao16  = (_Float16*)(ws + OFF_AO);
  float*    x1    = (float*)(ws + OFF_X1);
  _Float16* h16   = (_Float16*)(ws + OFF_H16);
  _Float16* w16   = (_Float16*)(ws + OFF_W16);
  float*    bqkv  = (float*)(ws + OFF_BQKV);
  float*    stats = (float*)(ws + OFF_STATS);
  float*    out   = (float*)d_out;

  const _Float16* wqkv16 = w16;
  const _Float16* wo16   = w16 + N_WQKV;
  const _Float16* w116   = w16 + N_WQKV + N_WO;
  const _Float16* w216   = w16 + N_WQKV + N_WO + N_W1;

  const dim3 blk256(256);

  convert_weights<<<768, blk256, 0, stream>>>(wq, wk, wv, wo, w1, w2, bq, bk, bv,
                                              w16, bqkv, stats);

  // Fused QKV projection: CO=768, K=256, fp32 x in, f16 out
  gemm_mfma<false, false, false, false, false, float, _Float16>
      <<<dim3(36, 12, 2), blk256, 0, stream>>>(
          wqkv16, x, bqkv, nullptr, qkv16, 3 * C, C, nullptr, nullptr, nullptr, nullptr);

  // Fused MFMA flash attention (incl. vn correction)
  attn_mfma<<<dim3(T / 64, BH), blk256, 0, stream>>>(qkv16, ao16);

  // Output projection + residual -> x1 raw; fused GN1 stats
  gemm_mfma<false, true, false, false, true, _Float16, float>
      <<<dim3(36, 4, 2), blk256, 0, stream>>>(
          wo16, ao16, bo, x, x1, C, C, nullptr, nullptr, nullptr, stats);

  // FFN1: GN1 applied to staged input, ReLU, f16 out
  gemm_mfma<true, false, true, false, false, float, _Float16>
      <<<dim3(36, 16, 2), blk256, 0, stream>>>(
          w116, x1, bf1, nullptr, h16, F, C, stats, gamma1, beta1, nullptr);

  // FFN2: + GN1(x1raw) residual -> d_out raw; fused GN2 stats
  gemm_mfma<false, true, false, true, true, _Float16, float>
      <<<dim3(36, 4, 2), blk256, 0, stream>>>(
          w216, h16, bf2, x1, out, C, F, stats, gamma1, beta1, stats + 4);

  // GN2 normalize in place on d_out
  gn_norm<<<dim3(4608), blk256, 0, stream>>>(out, stats + 4, gamma2, beta2, out);
}

// Round 4
// 134.605 us; speedup vs baseline: 4.0318x; 1.2571x over previous
//
#include <hip/hip_runtime.h>
#include <hip/hip_fp16.h>

typedef _Float16 f16x8 __attribute__((ext_vector_type(8)));
typedef float f32x4 __attribute__((ext_vector_type(4)));

namespace {

constexpr int B = 2, C = 256, T = 2304, F = 1024, NH = 8, HD = 32;
constexpr int BH = B * NH;           // 16
constexpr int NCHUNK = 4;
constexpr int CHUNK = T / NCHUNK;    // 576
constexpr float SCALE = 0.17677669529663687f;              // 1/sqrt(32)
constexpr float C2 = 0.17677669529663687f * 1.4426950408889634f;  // scale*log2(e)
constexpr float INV_N = 1.0f / (float)(C * T);

// f16 weight block sizes (flat elements)
constexpr size_t N_WQKV = (size_t)3 * C * C;   // 196608
constexpr size_t N_WO   = (size_t)C * C;       // 65536
constexpr size_t N_W1   = (size_t)F * C;       // 262144
constexpr size_t N_W2   = (size_t)C * F;       // 262144
constexpr size_t N_WALL = N_WQKV + N_WO + N_W1 + N_W2;

// workspace layout (bytes)
constexpr size_t OFF_QKV  = 0;                                // f16 [B][3C][T]
constexpr size_t SZ_QKV   = (size_t)B * 3 * C * T * 2;
constexpr size_t OFF_AO   = OFF_QKV + SZ_QKV;                 // f16 [B][C][T]
constexpr size_t SZ_AO    = (size_t)B * C * T * 2;
constexpr size_t OFF_X1   = OFF_AO + SZ_AO;                   // f32 [B][C][T] (raw, pre-GN1)
constexpr size_t SZ_X1    = (size_t)B * C * T * 4;
// union region: attention partials, later reused as FFN hidden h16
constexpr size_t OFF_PART = OFF_X1 + SZ_X1;
constexpr size_t SZ_OP    = (size_t)NCHUNK * BH * HD * T * 2; // f16 chunk-normalized O
constexpr size_t SZ_MP    = (size_t)NCHUNK * BH * T * 4;      // f32
constexpr size_t OFF_OP   = OFF_PART;
constexpr size_t OFF_MP   = OFF_OP + SZ_OP;
constexpr size_t OFF_LP   = OFF_MP + SZ_MP;
constexpr size_t SZ_H16   = (size_t)B * F * T * 2;
constexpr size_t SZ_PART  = SZ_OP + 2 * SZ_MP;
constexpr size_t SZ_UNION = SZ_PART > SZ_H16 ? SZ_PART : SZ_H16;
constexpr size_t OFF_H16  = OFF_PART;
constexpr size_t OFF_W16  = OFF_PART + SZ_UNION;              // f16 weights (qkv|wo|w1|w2)
constexpr size_t OFF_BQKV = OFF_W16 + N_WALL * 2;             // f32 [768]
constexpr size_t OFF_STATS = OFF_BQKV + (size_t)3 * C * 4;    // f32 [8]

} // namespace

// Convert all weights fp32 -> f16 into one flat buffer; concat qkv bias; zero stats.
__global__ __launch_bounds__(256)
void convert_weights(const float* __restrict__ wq, const float* __restrict__ wk,
                     const float* __restrict__ wv, const float* __restrict__ wo,
                     const float* __restrict__ w1, const float* __restrict__ w2,
                     const float* __restrict__ bq, const float* __restrict__ bk,
                     const float* __restrict__ bv,
                     _Float16* __restrict__ w16, float* __restrict__ bqkv,
                     float* __restrict__ stats)
{
  const size_t tid = (size_t)blockIdx.x * 256 + threadIdx.x;
  if (tid < 8) stats[tid] = 0.f;
  if (tid < 3 * C)
    bqkv[tid] = tid < C ? bq[tid] : (tid < 2 * C ? bk[tid - C] : bv[tid - 2 * C]);
  for (size_t i = tid; i < N_WALL; i += (size_t)gridDim.x * 256) {
    float v;
    if      (i < 65536)  v = wq[i];
    else if (i < 131072) v = wk[i - 65536];
    else if (i < 196608) v = wv[i - 131072];
    else if (i < 262144) v = wo[i - 196608];
    else if (i < 524288) v = w1[i - 262144];
    else                 v = w2[i - 524288];
    w16[i] = (_Float16)v;
  }
}

// out[b][co][t] = act( W[co][:] . X[b][:][t] + bias[co] (+ res') )
template<bool RELU, bool RES, bool GNIN, bool GNRES, bool STATS,
         typename InT, typename OutT>
__global__ __launch_bounds__(256)
void gemm_mfma(const _Float16* __restrict__ W, const InT* __restrict__ X,
               const float* __restrict__ bias, const float* __restrict__ res,
               OutT* __restrict__ out, int CO, int K,
               const float* __restrict__ stats_in,
               const float* __restrict__ gamma, const float* __restrict__ beta,
               float* __restrict__ stats_out)
{
  const int b   = blockIdx.z;
  const int co0 = blockIdx.y * 64;
  const int t0  = blockIdx.x * 64;
  const int tid = threadIdx.x;
  const int wid = tid >> 6, lane = tid & 63;
  const int g = lane >> 4, lo = lane & 15;
  const int wm = wid & 1, wn = wid >> 1;

  __shared__ f16x8 xs[4][64];      // [k/8][t] current 32-k step
  __shared__ float gs[256], bs[256];
  __shared__ float red[8];

  float mu = 0.f, rsig = 0.f;
  if (GNIN || GNRES) {
    const float s1 = stats_in[b * 2], s2 = stats_in[b * 2 + 1];
    mu = s1 * INV_N;
    rsig = rsqrtf(s2 * INV_N - mu * mu + 1e-5f);
  }
  if (GNIN) { gs[tid] = gamma[tid]; bs[tid] = beta[tid]; }

  const f32x4 z4 = {0.f, 0.f, 0.f, 0.f};
  f32x4 acc00 = z4, acc01 = z4, acc10 = z4, acc11 = z4;

  const int st = tid & 63;   // staged t within tile
  const int kp = tid >> 6;   // staged k/8 within step
  const InT* Xp = X + (size_t)b * K * T + t0 + st;
  const _Float16* Wp = W + (size_t)(co0 + wm * 32 + lo) * K + 8 * g;

  __syncthreads();   // gs/bs visible before staging uses them

  for (int k0 = 0; k0 < K; k0 += 32) {
    f16x8 wv_;
#pragma unroll
    for (int j = 0; j < 8; ++j) {
      const int k = k0 + kp * 8 + j;
      float v = (float)Xp[(size_t)k * T];
      if (GNIN) v = (v - mu) * rsig * gs[k] + bs[k];
      wv_[j] = (_Float16)v;
    }
    xs[kp][st] = wv_;
    __syncthreads();
    const f16x8 af0 = *(const f16x8*)(Wp + (size_t)k0);
    const f16x8 af1 = *(const f16x8*)(Wp + (size_t)16 * K + k0);
    const f16x8 bf0 = xs[g][wn * 32 + lo];
    const f16x8 bf1 = xs[g][wn * 32 + 16 + lo];
    acc00 = __builtin_amdgcn_mfma_f32_16x16x32_f16(af0, bf0, acc00, 0, 0, 0);
    acc01 = __builtin_amdgcn_mfma_f32_16x16x32_f16(af0, bf1, acc01, 0, 0, 0);
    acc10 = __builtin_amdgcn_mfma_f32_16x16x32_f16(af1, bf0, acc10, 0, 0, 0);
    acc11 = __builtin_amdgcn_mfma_f32_16x16x32_f16(af1, bf1, acc11, 0, 0, 0);
    __syncthreads();
  }

  float s = 0.f, ss = 0.f;
  const size_t obase = ((size_t)b * CO + co0 + wm * 32) * T + t0 + wn * 32 + lo;
  const float* resb = res + obase;   // valid only if RES
  OutT* outb = out + obase;
  const f32x4 accs[2][2] = {{acc00, acc01}, {acc10, acc11}};
#pragma unroll
  for (int mi = 0; mi < 2; ++mi) {
#pragma unroll
    for (int r = 0; r < 4; ++r) {
      const int row = mi * 16 + 4 * g + r;
      const int co = co0 + wm * 32 + row;
      const float bi = bias[co];
      float gm = 0.f, bt = 0.f;
      if (GNRES) { gm = gamma[co]; bt = beta[co]; }
#pragma unroll
      for (int ni = 0; ni < 2; ++ni) {
        float v = accs[mi][ni][r] + bi;
        if (RES) {
          float rv = resb[(size_t)row * T + ni * 16];
          if (GNRES) rv = (rv - mu) * rsig * gm + bt;
          v += rv;
        }
        if (RELU) v = fmaxf(v, 0.f);
        outb[(size_t)row * T + ni * 16] = (OutT)v;
        if (STATS) { s += v; ss = fmaf(v, v, ss); }
      }
    }
  }

  if (STATS) {
#pragma unroll
    for (int off = 32; off > 0; off >>= 1) {
      s  += __shfl_down(s, off);
      ss += __shfl_down(ss, off);
    }
    if (lane == 0) { red[wid] = s; red[4 + wid] = ss; }
    __syncthreads();
    if (tid == 0) {
      atomicAdd(&stats_out[b * 2],     red[0] + red[1] + red[2] + red[3]);
      atomicAdd(&stats_out[b * 2 + 1], red[4] + red[5] + red[6] + red[7]);
    }
  }
}

// Flash-attention partials over one key chunk (MFMA, exp2-domain softmax).
// QKV fused layout [B][3C][T] f16. Block: 4 waves x 16 queries.
// Writes chunk-normalized O (f16), m (base-2 running max), l.
__global__ __launch_bounds__(256)
void attn_mfma(const _Float16* __restrict__ qkv, _Float16* __restrict__ opart,
               float* __restrict__ mpart, float* __restrict__ lpart)
{
  const int tid  = threadIdx.x;
  const int wid  = tid >> 6;
  const int lane = tid & 63;
  const int g    = lane >> 4;
  const int lo   = lane & 15;
  const int chunk = blockIdx.y;
  const int bh   = blockIdx.z;
  const int b    = bh >> 3, h = bh & 7;
  const int tq   = blockIdx.x * 64 + wid * 16 + lo;
  const size_t qb = ((size_t)b * 3 * C + h * HD) * T;
  const size_t kb = qb + (size_t)C * T;
  const size_t vb = qb + (size_t)2 * C * T;

  __shared__ _Float16 kt[64][36];      // [tk][d] transposed K tile
  __shared__ _Float16 vt[32][72];      // [d][tk] V tile
  __shared__ _Float16 pl[4][16][72];   // per-wave P: [tq][tk]

  f16x8 qf;
#pragma unroll
  for (int j = 0; j < 8; ++j)
    qf[j] = qkv[qb + (size_t)(8 * g + j) * T + tq];

  const f32x4 zero4 = {0.f, 0.f, 0.f, 0.f};
  f32x4 oa[2] = {zero4, zero4};
  float m = -1e30f, l = 0.f;

  for (int it = 0; it < CHUNK / 64; ++it) {
    const int tk0 = chunk * CHUNK + it * 64;
    __syncthreads();
    {
      const int t = tid & 63;
      const int dp0 = tid >> 6;
#pragma unroll
      for (int dd = 0; dd < 4; ++dd) {
        const int d = (dp0 * 4 + dd) * 2;
        const ushort klo = *(const ushort*)(qkv + kb + (size_t)d * T + tk0 + t);
        const ushort khi = *(const ushort*)(qkv + kb + (size_t)(d + 1) * T + tk0 + t);
        *(uint*)&kt[t][d] = (uint)klo | ((uint)khi << 16);
      }
    }
    {
      const int dv = tid >> 3;
      const int seg = tid & 7;
      *(uint4*)&vt[dv][seg * 8] =
          *(const uint4*)(qkv + vb + (size_t)dv * T + tk0 + seg * 8);
    }
    __syncthreads();

    f32x4 s4[4];
#pragma unroll
    for (int mt = 0; mt < 4; ++mt) {
      union { f16x8 v; uint2 u[2]; } kf;
      const _Float16* kr = &kt[mt * 16 + lo][8 * g];
      kf.u[0] = *(const uint2*)(kr);
      kf.u[1] = *(const uint2*)(kr + 4);
      s4[mt] = __builtin_amdgcn_mfma_f32_16x16x32_f16(kf.v, qf, zero4, 0, 0, 0);
    }
    // lane holds S^T[tk = mt*16 + 4g + r][tq = lo]; base-2 domain
    float p[4][4];
    float rmax = -1e30f;
#pragma unroll
    for (int mt = 0; mt < 4; ++mt)
#pragma unroll
      for (int r = 0; r < 4; ++r) {
        p[mt][r] = s4[mt][r] * C2;
        rmax = fmaxf(rmax, p[mt][r]);
      }
    rmax = fmaxf(rmax, __shfl_xor(rmax, 16));
    rmax = fmaxf(rmax, __shfl_xor(rmax, 32));
    const float mn = fmaxf(m, rmax);
    const float fsc = __builtin_amdgcn_exp2f(m - mn);
    m = mn;
    float psum = 0.f;
#pragma unroll
    for (int mt = 0; mt < 4; ++mt)
#pragma unroll
      for (int r = 0; r < 4; ++r) {
        p[mt][r] = __builtin_amdgcn_exp2f(p[mt][r] - mn);
        psum += p[mt][r];
      }
    psum += __shfl_xor(psum, 16);
    psum += __shfl_xor(psum, 32);
    l = l * fsc + psum;
#pragma unroll
    for (int dt = 0; dt < 2; ++dt)
#pragma unroll
      for (int r = 0; r < 4; ++r) oa[dt][r] *= fsc;

    // P -> per-wave LDS (b64 writes), then read B-fragments (b128)
#pragma unroll
    for (int mt = 0; mt < 4; ++mt) {
      union { _Float16 e[4]; uint2 u2; } pw;
#pragma unroll
      for (int r = 0; r < 4; ++r) pw.e[r] = (_Float16)p[mt][r];
      *(uint2*)&pl[wid][lo][16 * mt + 4 * g] = pw.u2;
    }
#pragma unroll
    for (int c2 = 0; c2 < 2; ++c2) {
      const f16x8 pbv = *(const f16x8*)&pl[wid][lo][c2 * 32 + 8 * g];
#pragma unroll
      for (int dt = 0; dt < 2; ++dt) {
        const f16x8 vf = *(const f16x8*)&vt[dt * 16 + lo][c2 * 32 + 8 * g];
        oa[dt] = __builtin_amdgcn_mfma_f32_16x16x32_f16(vf, pbv, oa[dt], 0, 0, 0);
      }
    }
  }

  // epilogue: store chunk-normalized O (f16) + m,l
  const float invL = 1.f / l;
  const size_t ob = (size_t)(chunk * BH + bh) * HD * T;
#pragma unroll
  for (int dt = 0; dt < 2; ++dt)
#pragma unroll
    for (int r = 0; r < 4; ++r)
      opart[ob + (size_t)(dt * 16 + 4 * g + r) * T + tq] =
          (_Float16)(oa[dt][r] * invL);
  if (g == 0) {
    const size_t pb = (size_t)(chunk * BH + bh) * T + tq;
    mpart[pb] = m;
    lpart[pb] = l;
  }
}

// Combine chunk partials + remove component along normalized v (fp16 cast points).
__global__ __launch_bounds__(64)
void attn_combine(const _Float16* __restrict__ opart, const float* __restrict__ mpart,
                  const float* __restrict__ lpart, const _Float16* __restrict__ qkv,
                  _Float16* __restrict__ AOh)
{
  const int q  = blockIdx.x * 64 + threadIdx.x;
  const int bh = blockIdx.y;
  const int b  = bh >> 3, h = bh & 7;
  float mv[NCHUNK], lv[NCHUNK];
  float M = -1e30f;
#pragma unroll
  for (int c = 0; c < NCHUNK; ++c) {
    const size_t pb = (size_t)(c * BH + bh) * T + q;
    mv[c] = mpart[pb];
    lv[c] = lpart[pb];
    M = fmaxf(M, mv[c]);
  }
  float L = 0.f;
  float wc[NCHUNK];
#pragma unroll
  for (int c = 0; c < NCHUNK; ++c) {
    wc[c] = __builtin_amdgcn_exp2f(mv[c] - M) * lv[c];
    L += wc[c];
  }
  const float inv = 1.f / L;
#pragma unroll
  for (int c = 0; c < NCHUNK; ++c) wc[c] *= inv;

  float o[HD];
#pragma unroll
  for (int d = 0; d < HD; ++d) o[d] = 0.f;
#pragma unroll
  for (int c = 0; c < NCHUNK; ++c) {
    const size_t ob = (size_t)(c * BH + bh) * HD * T + q;
#pragma unroll
    for (int d = 0; d < HD; ++d)
      o[d] = fmaf(wc[c], (float)opart[ob + (size_t)d * T], o[d]);
  }

  const size_t vbase = ((size_t)b * 3 * C + 2 * C + h * HD) * T + q;
  float vv[HD], nrm2 = 0.f;
#pragma unroll
  for (int d = 0; d < HD; ++d) {
    vv[d] = (float)qkv[vbase + (size_t)d * T];
    nrm2 = fmaf(vv[d], vv[d], nrm2);
  }
  const float nrm = fmaxf(sqrtf(nrm2), 1e-12f);
  float dot = 0.f;
  float o16[HD], vn[HD];
#pragma unroll
  for (int d = 0; d < HD; ++d) {
    o16[d] = (float)(_Float16)(o[d]);
    vn[d]  = (float)(_Float16)(vv[d] / nrm);
    dot = fmaf(o16[d], vn[d], dot);
  }
  const size_t ab = ((size_t)b * C + h * HD) * T + q;
#pragma unroll
  for (int d = 0; d < HD; ++d)
    AOh[ab + (size_t)d * T] = (_Float16)(o16[d] - dot * vn[d]);
}

__global__ __launch_bounds__(256)
void gn_norm(const float* __restrict__ Y, const float* __restrict__ stats,
             const float* __restrict__ gamma, const float* __restrict__ beta,
             float* __restrict__ O)
{
  const int i = blockIdx.x * 256 + threadIdx.x;
  const int b = i / (C * T);
  const int c = (i / T) & (C - 1);
  const float mu  = stats[b * 2] * INV_N;
  const float var = stats[b * 2 + 1] * INV_N - mu * mu;
  const float r = rsqrtf(var + 1e-5f);
  O[i] = (Y[i] - mu) * r * gamma[c] + beta[c];
}

extern "C" void kernel_launch(void* const* d_in, const int* in_sizes, int n_in,
                              void* d_out, int out_size, void* d_ws, size_t ws_size,
                              hipStream_t stream)
{
  const float* x      = (const float*)d_in[0];
  const float* wq     = (const float*)d_in[1];
  const float* bq     = (const float*)d_in[2];
  const float* wk     = (const float*)d_in[3];
  const float* bk     = (const float*)d_in[4];
  const float* wv     = (const float*)d_in[5];
  const float* bv     = (const float*)d_in[6];
  const float* wo     = (const float*)d_in[7];
  const float* bo     = (const float*)d_in[8];
  const float* gamma1 = (const float*)d_in[9];
  const float* beta1  = (const float*)d_in[10];
  const float* w1     = (const float*)d_in[11];
  const float* bf1    = (const float*)d_in[12];
  const float* w2     = (const float*)d_in[13];
  const float* bf2    = (const float*)d_in[14];
  const float* gamma2 = (const float*)d_in[15];
  const float* beta2  = (const float*)d_in[16];

  char* ws = (char*)d_ws;
  _Float16* qkv16 = (_Float16*)(ws + OFF_QKV);
  _Float16* ao16  = (_Float16*)(ws + OFF_AO);
  float*    x1    = (float*)(ws + OFF_X1);
  _Float16* opart = (_Float16*)(ws + OFF_OP);
  float*    mpart = (float*)(ws + OFF_MP);
  float*    lpart = (float*)(ws + OFF_LP);
  _Float16* h16   = (_Float16*)(ws + OFF_H16);
  _Float16* w16   = (_Float16*)(ws + OFF_W16);
  float*    bqkv  = (float*)(ws + OFF_BQKV);
  float*    stats = (float*)(ws + OFF_STATS);
  float*    out   = (float*)d_out;

  const _Float16* wqkv16 = w16;
  const _Float16* wo16   = w16 + N_WQKV;
  const _Float16* w116   = w16 + N_WQKV + N_WO;
  const _Float16* w216   = w16 + N_WQKV + N_WO + N_W1;

  const dim3 blk256(256);

  convert_weights<<<768, blk256, 0, stream>>>(wq, wk, wv, wo, w1, w2, bq, bk, bv,
                                              w16, bqkv, stats);

  // Fused QKV projection: CO=768, K=256, fp32 x in, f16 out
  gemm_mfma<false, false, false, false, false, float, _Float16>
      <<<dim3(36, 12, 2), blk256, 0, stream>>>(
          wqkv16, x, bqkv, nullptr, qkv16, 3 * C, C, nullptr, nullptr, nullptr, nullptr);

  // Flash attention partials (4-way key split) + combine (incl. vn correction)
  attn_mfma<<<dim3(T / 64, NCHUNK, BH), blk256, 0, stream>>>(qkv16, opart, mpart, lpart);
  attn_combine<<<dim3(T / 64, BH), dim3(64), 0, stream>>>(opart, mpart, lpart, qkv16, ao16);

  // Output projection + residual -> x1 raw; fused GN1 stats
  gemm_mfma<false, true, false, false, true, _Float16, float>
      <<<dim3(36, 4, 2), blk256, 0, stream>>>(
          wo16, ao16, bo, x, x1, C, C, nullptr, nullptr, nullptr, stats);

  // FFN1: GN1 applied to staged input, ReLU, f16 out
  gemm_mfma<true, false, true, false, false, float, _Float16>
      <<<dim3(36, 16, 2), blk256, 0, stream>>>(
          w116, x1, bf1, nullptr, h16, F, C, stats, gamma1, beta1, nullptr);

  // FFN2: + GN1(x1raw) residual -> d_out raw; fused GN2 stats
  gemm_mfma<false, true, false, true, true, _Float16, float>
      <<<dim3(36, 4, 2), blk256, 0, stream>>>(
          w216, h16, bf2, x1, out, C, F, stats, gamma1, beta1, stats + 4);

  // GN2 normalize in place on d_out
  gn_norm<<<dim3(4608), blk256, 0, stream>>>(out, stats + 4, gamma2, beta2, out);
}